// Round 2
// baseline (1295.937 us; speedup 1.0000x reference)
//
#include <hip/hip_runtime.h>

// Outputs (concatenated flat in d_out, all float32):
//   loss     [B*16]      = (x - y)^2
//   d_loss   [B*16]      = 2*(x - y)
//   sqd_loss [B*16*16]   = per-sample Hessian = 2*I_16 (input-independent)
//
// Single persistent-style kernel, grid-stride, grid capped at 2048 blocks
// (G11: memory-bound -> 8 blocks/CU; avoids 262k one-shot-workgroup churn).
// Uses clang ext_vector_type (not HIP float4) so __builtin_nontemporal_store
// accepts the pointer type.

typedef float v4f __attribute__((ext_vector_type(4)));

__global__ __launch_bounds__(256) void fused_loss_hess(
    const v4f* __restrict__ x,
    const v4f* __restrict__ y,
    v4f* __restrict__ loss,
    v4f* __restrict__ dloss,
    v4f* __restrict__ sqd,
    unsigned int n4_ld,   // BD/4 float4s of loss/dloss
    unsigned int n4_h) {  // BD*16/4 float4s of sqd_loss
    const unsigned int T   = gridDim.x * blockDim.x;           // 524288
    const unsigned int tid = blockIdx.x * blockDim.x + threadIdx.x;

    // ---- Phase A: loss + d_loss (128 MiB read, 128 MiB write) ----
    for (unsigned int i = tid; i < n4_ld; i += T) {
        v4f a = x[i];
        v4f b = y[i];
        v4f d = a - b;
        v4f l = d * d;
        v4f g = d + d;
        __builtin_nontemporal_store(l, &loss[i]);
        __builtin_nontemporal_store(g, &dloss[i]);
    }

    // ---- Phase B: Hessian = 2*I_16 per 256-float block (1 GiB write) ----
    // Flat float index f: row = (f>>4)&15, col = f&15. A float4 at base f
    // (f%4==0) has all 4 elements in one row. The pattern for float4 index
    // i depends only on i % 64; T is a multiple of 64, so each thread's
    // value is loop-invariant: compute once, stream stores.
    {
        const unsigned int f   = tid << 2;
        const unsigned int col = f & 15u;          // 0,4,8,12
        const unsigned int row = (f >> 4) & 15u;
        v4f v;
        v.x = (row == col)      ? 2.0f : 0.0f;
        v.y = (row == col + 1u) ? 2.0f : 0.0f;
        v.z = (row == col + 2u) ? 2.0f : 0.0f;
        v.w = (row == col + 3u) ? 2.0f : 0.0f;
#pragma unroll 8
        for (unsigned int i = tid; i < n4_h; i += T) {
            __builtin_nontemporal_store(v, &sqd[i]);
        }
    }
}

extern "C" void kernel_launch(void* const* d_in, const int* in_sizes, int n_in,
                              void* d_out, int out_size, void* d_ws, size_t ws_size,
                              hipStream_t stream) {
    const float* model_out = (const float*)d_in[0];
    const float* y_true    = (const float*)d_in[1];
    float* out = (float*)d_out;

    const int BD = in_sizes[0];              // B*16 = 16,777,216
    float* loss_p  = out;                    // [BD]
    float* dloss_p = out + BD;               // [BD]
    float* sqd_p   = out + 2 * (size_t)BD;   // [BD*16]

    const unsigned int n4_ld = (unsigned int)(BD / 4);                 // 4,194,304
    const unsigned int n4_h  = (unsigned int)((size_t)BD * 16 / 4);    // 67,108,864

    const int block = 256;
    const int grid  = 2048;                  // 8 blocks/CU on 256 CUs
    fused_loss_hess<<<grid, block, 0, stream>>>(
        (const v4f*)model_out, (const v4f*)y_true,
        (v4f*)loss_p, (v4f*)dloss_p, (v4f*)sqd_p,
        n4_ld, n4_h);
}

// Round 3
// 1289.521 us; speedup vs baseline: 1.0050x; 1.0050x over previous
//
#include <hip/hip_runtime.h>

// Outputs (concatenated flat in d_out, all float32):
//   loss     [B*16]      = (x - y)^2
//   d_loss   [B*16]      = 2*(x - y)
//   sqd_loss [B*16*16]   = per-sample Hessian = 2*I_16 (input-independent)
//
// Persistent fused kernel, 2048 blocks x 256 threads, grid-stride.
// R2 lesson: __builtin_nontemporal_store regressed write BW (~3 TB/s on the
// pure-write phase vs 6.2 TB/s for plain stores) -- nt bypasses L2 line
// coalescing. All stores are now plain vector stores.

typedef float v4f __attribute__((ext_vector_type(4)));

__global__ __launch_bounds__(256) void fused_loss_hess(
    const v4f* __restrict__ x,
    const v4f* __restrict__ y,
    v4f* __restrict__ loss,
    v4f* __restrict__ dloss,
    v4f* __restrict__ sqd,
    unsigned int n4_ld,   // BD/4 float4s of loss/dloss
    unsigned int n4_h) {  // BD*16/4 float4s of sqd_loss
    const unsigned int T   = gridDim.x * blockDim.x;           // 524288
    const unsigned int tid = blockIdx.x * blockDim.x + threadIdx.x;

    // ---- Phase A: loss + d_loss (128 MiB read, 128 MiB write) ----
    for (unsigned int i = tid; i < n4_ld; i += T) {
        v4f a = x[i];
        v4f b = y[i];
        v4f d = a - b;
        loss[i]  = d * d;
        dloss[i] = d + d;
    }

    // ---- Phase B: Hessian = 2*I_16 per 256-float block (1 GiB write) ----
    // Flat float index f: row = (f>>4)&15, col = f&15. A float4 at base f
    // (f%4==0) has all 4 elements in one row. The pattern for float4 index
    // i depends only on i % 64; T is a multiple of 64, so each thread's
    // value is loop-invariant: compute once, stream stores.
    {
        const unsigned int f   = tid << 2;
        const unsigned int col = f & 15u;          // 0,4,8,12
        const unsigned int row = (f >> 4) & 15u;
        v4f v;
        v.x = (row == col)      ? 2.0f : 0.0f;
        v.y = (row == col + 1u) ? 2.0f : 0.0f;
        v.z = (row == col + 2u) ? 2.0f : 0.0f;
        v.w = (row == col + 3u) ? 2.0f : 0.0f;
#pragma unroll 8
        for (unsigned int i = tid; i < n4_h; i += T) {
            sqd[i] = v;
        }
    }
}

extern "C" void kernel_launch(void* const* d_in, const int* in_sizes, int n_in,
                              void* d_out, int out_size, void* d_ws, size_t ws_size,
                              hipStream_t stream) {
    const float* model_out = (const float*)d_in[0];
    const float* y_true    = (const float*)d_in[1];
    float* out = (float*)d_out;

    const int BD = in_sizes[0];              // B*16 = 16,777,216
    float* loss_p  = out;                    // [BD]
    float* dloss_p = out + BD;               // [BD]
    float* sqd_p   = out + 2 * (size_t)BD;   // [BD*16]

    const unsigned int n4_ld = (unsigned int)(BD / 4);                 // 4,194,304
    const unsigned int n4_h  = (unsigned int)((size_t)BD * 16 / 4);    // 67,108,864

    const int block = 256;
    const int grid  = 2048;                  // 8 blocks/CU on 256 CUs
    fused_loss_hess<<<grid, block, 0, stream>>>(
        (const v4f*)model_out, (const v4f*)y_true,
        (v4f*)loss_p, (v4f*)dloss_p, (v4f*)sqd_p,
        n4_ld, n4_h);
}

// Round 6
// 1268.514 us; speedup vs baseline: 1.0216x; 1.0166x over previous
//
#include <hip/hip_runtime.h>

// Outputs (concatenated flat in d_out, all float32):
//   loss     [B*16]      = (x - y)^2
//   d_loss   [B*16]      = 2*(x - y)
//   sqd_loss [B*16*16]   = per-sample Hessian = 2*I_16 (input-independent)
//
// R3 lessons: NT stores were a ~6us nothing; the fused persistent grid-stride
// structure cost ~56us vs the R0 one-shot pair. This round tests whether the
// rocclr-fill structure (few waves, each streaming a long CONTIGUOUS run with
// deep store pipelining) unlocks 6.2 TB/s pure-write for the 1.07 GB Hessian,
// vs the ~2.6 TB/s our scattered-wave versions achieve.
// (R4/R5 were infra failures — identical resubmission, kernel audited clean.)

typedef float v4f __attribute__((ext_vector_type(4)));

// ---- Phase A: fused loss + d_loss, one-shot grid (identical to R0) ----
__global__ __launch_bounds__(256) void loss_grad_kernel(
    const v4f* __restrict__ x,
    const v4f* __restrict__ y,
    v4f* __restrict__ loss,
    v4f* __restrict__ dloss,
    int n4) {
    int i = blockIdx.x * blockDim.x + threadIdx.x;
    if (i >= n4) return;
    v4f a = x[i];
    v4f b = y[i];
    v4f d = a - b;
    loss[i]  = d * d;
    dloss[i] = d + d;
}

// ---- Phase B: Hessian = 2*I_16, wave-chunked contiguous stream fill ----
// Each wave owns a contiguous chunk of `chunk` float4s (chunk % 256 == 0,
// wave base is 1KB-aligned so the 16x16-matrix phase is lane-determined).
// Inner loop: 4 stores off one base pointer at +0/+1024/+2048/+3072 bytes
// (13-bit imm offsets), then bump base by 4KB. Store data is loop-invariant.
__global__ __launch_bounds__(256) void hess_stream_fill(
    v4f* __restrict__ out, unsigned int chunk /* float4s per wave */) {
    const unsigned int lane = threadIdx.x & 63u;
    const unsigned int wpb  = blockDim.x >> 6;                 // waves per block
    const unsigned int wid  = blockIdx.x * wpb + (threadIdx.x >> 6);

    // Value for this lane: float4 index within a 256-float matrix == lane.
    const unsigned int f   = lane << 2;
    const unsigned int col = f & 15u;          // 0,4,8,12
    const unsigned int row = (f >> 4) & 15u;
    v4f v;
    v.x = (row == col)      ? 2.0f : 0.0f;
    v.y = (row == col + 1u) ? 2.0f : 0.0f;
    v.z = (row == col + 2u) ? 2.0f : 0.0f;
    v.w = (row == col + 3u) ? 2.0f : 0.0f;

    v4f* p = out + (size_t)wid * chunk + lane;
    const unsigned int iters = chunk >> 8;     // 256 float4s (4KB) per iter
    for (unsigned int it = 0; it < iters; ++it) {
        p[0]   = v;        // +0B
        p[64]  = v;        // +1024B
        p[128] = v;        // +2048B
        p[192] = v;        // +3072B
        p += 256;          // +4096B
    }
}

// ---- Fallback: R0 one-shot pattern fill (for non-dividing sizes) ----
__global__ __launch_bounds__(256) void hess_fill_kernel(
    v4f* __restrict__ out, unsigned int n4) {
    unsigned int i = blockIdx.x * blockDim.x + threadIdx.x;
    if (i >= n4) return;
    unsigned int ff  = i << 2;
    unsigned int col = ff & 15u;
    unsigned int row = (ff >> 4) & 15u;
    v4f v;
    v.x = (row == col)      ? 2.0f : 0.0f;
    v.y = (row == col + 1u) ? 2.0f : 0.0f;
    v.z = (row == col + 2u) ? 2.0f : 0.0f;
    v.w = (row == col + 3u) ? 2.0f : 0.0f;
    out[i] = v;
}

extern "C" void kernel_launch(void* const* d_in, const int* in_sizes, int n_in,
                              void* d_out, int out_size, void* d_ws, size_t ws_size,
                              hipStream_t stream) {
    const float* model_out = (const float*)d_in[0];
    const float* y_true    = (const float*)d_in[1];
    float* out = (float*)d_out;

    const int BD = in_sizes[0];              // B*16 = 16,777,216
    float* loss_p  = out;                    // [BD]
    float* dloss_p = out + BD;               // [BD]
    float* sqd_p   = out + 2 * (size_t)BD;   // [BD*16]

    // Kernel 1: fused loss + d_loss (one-shot, float4)
    {
        int n4 = BD / 4;                     // 4,194,304
        int block = 256;
        int grid = (n4 + block - 1) / block; // 16384
        loss_grad_kernel<<<grid, block, 0, stream>>>(
            (const v4f*)model_out, (const v4f*)y_true,
            (v4f*)loss_p, (v4f*)dloss_p, n4);
    }

    // Kernel 2: Hessian fill
    {
        unsigned int n4 = (unsigned int)((size_t)BD * 16 / 4); // 67,108,864
        const int block  = 256;
        const int grid   = 1024;                               // 4096 waves
        const unsigned int nw = (unsigned int)grid * (block / 64);
        if (n4 % (nw * 256u) == 0u) {
            // 262,144B contiguous per wave; 64 iterations of 4KB
            unsigned int chunk = n4 / nw;                      // 16384 float4s
            hess_stream_fill<<<grid, block, 0, stream>>>((v4f*)sqd_p, chunk);
        } else {
            unsigned int g = (n4 + block - 1) / block;
            hess_fill_kernel<<<g, block, 0, stream>>>((v4f*)sqd_p, n4);
        }
    }
}

// Round 9
// 1226.768 us; speedup vs baseline: 1.0564x; 1.0340x over previous
//
#include <hip/hip_runtime.h>

// Outputs (concatenated flat in d_out, all float32):
//   loss     [B*16]      = (x - y)^2
//   d_loss   [B*16]      = 2*(x - y)
//   sqd_loss [B*16*16]   = per-sample Hessian = 2*I_16 (input-independent)
//
// Session scoreboard ("our share" = total - ~783us harness poison fill):
//   R0 one-shot pair        450us   <- best
//   R6 wave-chunked stream  485us
//   R3 persistent plain     506us
//   R2 persistent + NT      513us
// Store-schedule theories (grid churn, NT, stream locality) all falsified.
// This round: fuse R0's two one-shot kernels into ONE launch (remove the
// inter-kernel serialization boundary; overlap the read stream with the
// pure-write stream). Mapping and arithmetic identical to R0 -> absmax 0.
// (R7/R8 were infra failures — identical resubmission, kernel audited clean;
// precedent: R4/R5 failed identically on a kernel that then ran fine in R6.)

typedef float v4f __attribute__((ext_vector_type(4)));

__global__ __launch_bounds__(256) void fused_oneshot(
    const v4f* __restrict__ x,
    const v4f* __restrict__ y,
    v4f* __restrict__ loss,
    v4f* __restrict__ dloss,
    v4f* __restrict__ sqd,
    unsigned int n4_ld,   // BD/4     = 4,194,304
    unsigned int n4_h) {  // BD*16/4  = 67,108,864
    const unsigned int i = blockIdx.x * blockDim.x + threadIdx.x;
    if (i >= n4_h) return;

    // Hessian pattern store (identical mapping to R0's hess_fill_kernel):
    // flat float index f = 4*i; all 4 elements share row (f>>4)&15,
    // cols f&15 .. (f&15)+3.
    const unsigned int f   = i << 2;
    const unsigned int col = f & 15u;          // 0,4,8,12
    const unsigned int row = (f >> 4) & 15u;
    v4f v;
    v.x = (row == col)      ? 2.0f : 0.0f;
    v.y = (row == col + 1u) ? 2.0f : 0.0f;
    v.z = (row == col + 2u) ? 2.0f : 0.0f;
    v.w = (row == col + 3u) ? 2.0f : 0.0f;
    sqd[i] = v;

    // First n4_ld threads also produce loss + d_loss (R0's loss_grad_kernel).
    if (i < n4_ld) {
        v4f a = x[i];
        v4f b = y[i];
        v4f d = a - b;
        loss[i]  = d * d;
        dloss[i] = d + d;
    }
}

extern "C" void kernel_launch(void* const* d_in, const int* in_sizes, int n_in,
                              void* d_out, int out_size, void* d_ws, size_t ws_size,
                              hipStream_t stream) {
    const float* model_out = (const float*)d_in[0];
    const float* y_true    = (const float*)d_in[1];
    float* out = (float*)d_out;

    const int BD = in_sizes[0];              // B*16 = 16,777,216
    float* loss_p  = out;                    // [BD]
    float* dloss_p = out + BD;               // [BD]
    float* sqd_p   = out + 2 * (size_t)BD;   // [BD*16]

    const unsigned int n4_ld = (unsigned int)(BD / 4);              // 4,194,304
    const unsigned int n4_h  = (unsigned int)((size_t)BD * 16 / 4); // 67,108,864

    const int block = 256;
    const unsigned int grid = (n4_h + block - 1) / block;           // 262,144
    fused_oneshot<<<grid, block, 0, stream>>>(
        (const v4f*)model_out, (const v4f*)y_true,
        (v4f*)loss_p, (v4f*)dloss_p, (v4f*)sqd_p,
        n4_ld, n4_h);
}